// Round 18
// baseline (179.585 us; speedup 1.0000x reference)
//
#include <hip/hip_runtime.h>
#include <hip/hip_bf16.h>
#include <math.h>

#define B_      4
#define SD_     2048
#define SE_     2048
#define HIDIN   300
#define HIDMID  512
#define NH      8
#define DH      64
#define ESZ     ((size_t)4194304)          // elems per [32][2048][64] tensor
#define BUFB    24576                       // bytes per attn LDS buffer (Kh+Kl+V)

typedef __attribute__((ext_vector_type(8)))  short          s16x8;
typedef __attribute__((ext_vector_type(8)))  unsigned short u16x8;
typedef __attribute__((ext_vector_type(4)))  unsigned short u16x4;
typedef __attribute__((ext_vector_type(4)))  float          f32x4;
typedef __attribute__((ext_vector_type(16))) float          f32x16;

#define MFMA16 __builtin_amdgcn_mfma_f32_16x16x32_bf16
#define MFMA32 __builtin_amdgcn_mfma_f32_32x32x16_bf16

// logit scale: (1/sqrt(300)) * log2(e)  -> softmax done in base-2
#define QSCALE  0.0832940411f
#define NEGL   -1.4426950e9f               // -1e9 * log2e
#define DEFER_THR 24.0f                    // defer-max threshold (base-2 units)

__device__ __forceinline__ unsigned short f2bf(float f) {
    unsigned int u = __float_as_uint(f);
    u += 0x7fffu + ((u >> 16) & 1u);          // RNE
    return (unsigned short)(u >> 16);
}
__device__ __forceinline__ float bf2f(unsigned short s) {
    return __uint_as_float((unsigned int)s << 16);
}
__device__ __forceinline__ void gload16(const void* g, void* l) {
    __builtin_amdgcn_global_load_lds(
        (const __attribute__((address_space(1))) void*)g,
        (__attribute__((address_space(3))) void*)l, 16, 0, 0);
}
// Raw v_exp_f32 (no OCML denormal fixup): softmax-safe (underflow -> 0).
__device__ __forceinline__ float fexp2(float x) {
#if __has_builtin(__builtin_amdgcn_exp2f)
    return __builtin_amdgcn_exp2f(x);
#else
    return exp2f(x);
#endif
}

// ws ushort offsets
#define OF_QH   ((size_t)0)
#define OF_QL   (ESZ)
#define OF_KH   (2*ESZ)
#define OF_KL   (3*ESZ)
#define OF_VT   (4*ESZ)
#define OF_CA   (5*ESZ)                    // deH,deL,enH,enL (4 x 2621440)
#define OF_CW   (OF_CA + 10485760)         // WQh,WQl,WKh,WKl,WVh,WVl (6 x 163840)
#define OF_WOT  (OF_CW + 983040)           // 196608

// ---------------------------------------------------------------------------
// Kernel 0 (after proj; lives in dead conv-A ws): mask -> bf16-pair bias
// table in 32x32-MFMA register order. Per (qg=q>>5, t64): lane (hi, q&31)
// loads 4 uint4 (L=0..3); word w=L*4+i covers S regs (2(w&7), +1) of tile
// (w>>3):  t = (w>>3)*32 + 2*(w&1) + 8*((w&7)>>1) + 4*hi  (pair t, t+1).
// uint4 index = (((q>>5)*32 + t64)*4 + L)*64 + hi*32 + (q&31).
// ---------------------------------------------------------------------------
__global__ __launch_bounds__(256) void bias_kernel(const int* __restrict__ mask,
                                                   unsigned int* __restrict__ BiasT)
{
    const int idx = blockIdx.x * 256 + threadIdx.x;    // 65536 threads
    const int q = idx >> 5, t64 = idx & 31;
    const int* __restrict__ mrow = mask + (size_t)q * SE_ + t64 * 64;
    const unsigned int NEGB = (unsigned int)f2bf(NEGL);
    int mv[64];
#pragma unroll
    for (int i = 0; i < 16; ++i) {
        const int4 mm = *(const int4*)(mrow + i * 4);
        mv[i*4+0] = mm.x; mv[i*4+1] = mm.y; mv[i*4+2] = mm.z; mv[i*4+3] = mm.w;
    }
    uint4* __restrict__ dst4 = (uint4*)BiasT;
    const size_t cbase = ((size_t)(q >> 5) * 32 + t64) * 4;
#pragma unroll
    for (int hi = 0; hi < 2; ++hi) {
#pragma unroll
        for (int L = 0; L < 4; ++L) {
            unsigned int wd[4];
#pragma unroll
            for (int i = 0; i < 4; ++i) {
                const int w = L * 4 + i;
                const int t0 = (w >> 3) * 32 + 2 * (w & 1) + 8 * ((w & 7) >> 1) + 4 * hi;
                wd[i] = (mv[t0] ? NEGB : 0u) | ((mv[t0 + 1] ? NEGB : 0u) << 16);
            }
            dst4[(cbase + L) * 64 + hi * 32 + (q & 31)] =
                make_uint4(wd[0], wd[1], wd[2], wd[3]);
        }
    }
}

// ---------------------------------------------------------------------------
// Kernel 1a: de/en fp32 -> split bf16 hi/lo, tiled GEMM-A layout. (unchanged)
// ---------------------------------------------------------------------------
__global__ __launch_bounds__(256) void convA_kernel(
    const float* __restrict__ de, const float* __restrict__ en,
    unsigned short* __restrict__ CA)
{
    const int idx = blockIdx.x * 256 + threadIdx.x;    // 81920 per matrix
    const int mat = blockIdx.y;
    const float* __restrict__ A = mat ? en : de;
    unsigned short* __restrict__ H = CA + (size_t)mat * 5242880;
    unsigned short* __restrict__ L = H + 2621440;
    const int row = idx / 10, ch = idx - row * 10;
    float v[32];
    if (ch < 9) {
#pragma unroll
        for (int i = 0; i < 8; ++i) {
            const float4 f = *(const float4*)(A + (size_t)row * 300 + ch * 32 + i * 4);
            v[i*4+0] = f.x; v[i*4+1] = f.y; v[i*4+2] = f.z; v[i*4+3] = f.w;
        }
    } else {
#pragma unroll
        for (int i = 0; i < 32; ++i) {
            const int k = 288 + i;
            v[i] = (k < 300) ? A[(size_t)row * 300 + k] : 0.f;
        }
    }
    const int r128 = row & 127;
    const int xr = (r128 >> 1) & 3;
    const size_t tb = ((size_t)(row >> 7) * 10 + ch) * 4096 + r128 * 32;
#pragma unroll
    for (int sub = 0; sub < 4; ++sub) {
        const int slot = sub ^ xr;
        u16x8 hv, lv;
#pragma unroll
        for (int e = 0; e < 8; ++e) {
            const float f = v[sub * 8 + e];
            const unsigned short h = f2bf(f);
            hv[e] = h; lv[e] = f2bf(f - bf2f(h));
        }
        *(u16x8*)(H + tb + slot * 8) = hv;
        *(u16x8*)(L + tb + slot * 8) = lv;
    }
}

// ---------------------------------------------------------------------------
// Kernel 1b: weights conversion (unchanged).
// ---------------------------------------------------------------------------
__global__ __launch_bounds__(256) void convW_kernel(
    const float* __restrict__ WQ, const float* __restrict__ WK,
    const float* __restrict__ WV, const float* __restrict__ WO,
    unsigned short* __restrict__ CW, unsigned short* __restrict__ WOT)
{
    const int idx = blockIdx.x * 256 + threadIdx.x;
    if (idx < 122880) {
        const int which = idx / 40960;
        const int rem = idx - which * 40960;
        const int k = rem >> 7;
        const int n0 = (rem & 127) * 4;
        const float* __restrict__ W = which == 0 ? WQ : (which == 1 ? WK : WV);
        unsigned short* __restrict__ H = CW + (size_t)which * 327680;
        unsigned short* __restrict__ L = H + 163840;
        const float sc = (which == 0) ? QSCALE : 1.f;
        float4 w = make_float4(0.f, 0.f, 0.f, 0.f);
        if (k < 300) w = *(const float4*)(W + (size_t)k * 512 + n0);
        const float wv4[4] = {w.x * sc, w.y * sc, w.z * sc, w.w * sc};
        const int ch = k >> 5, kk = k & 31;
#pragma unroll
        for (int j = 0; j < 4; ++j) {
            const int n = n0 + j, ntile = n >> 7, nr = n & 127;
            const size_t o = ((size_t)(ntile * 10 + ch) * 128 + nr) * 32
                           + (((kk >> 3) ^ ((nr >> 1) & 3)) << 3) + (kk & 7);
            const unsigned short h = f2bf(wv4[j]);
            H[o] = h;
            if (which < 2) L[o] = f2bf(wv4[j] - bf2f(h));
        }
    } else {
        const int idx2 = idx - 122880;
        const int k = idx2 / 96, n4 = idx2 - k * 96;
        const int n0 = n4 * 4;
        float4 w = make_float4(0.f, 0.f, 0.f, 0.f);
        if (n0 < 300) w = *(const float4*)(WO + (size_t)k * 300 + n0);
        const float wv4[4] = {w.x, w.y, w.z, w.w};
        const int ch = k >> 5, kk = k & 31;
#pragma unroll
        for (int j = 0; j < 4; ++j) {
            const int n = n0 + j, ntile = n >> 7, nr = n & 127;
            const size_t o = ((size_t)(ntile * 16 + ch) * 128 + nr) * 32
                           + (((kk >> 3) ^ ((nr >> 1) & 3)) << 3) + (kk & 7);
            WOT[o] = f2bf(wv4[j]);
        }
    }
}

// ---------------------------------------------------------------------------
// Kernel 2a: MFMA Q/K projection (3-term, unchanged; K swizzle is shared by
// the 32x32 read pattern).
// ---------------------------------------------------------------------------
__global__ __launch_bounds__(256) void proj_qk_kernel(
    const unsigned short* __restrict__ CA, const unsigned short* __restrict__ CW,
    unsigned short* __restrict__ Qh, unsigned short* __restrict__ Ql,
    unsigned short* __restrict__ KhT, unsigned short* __restrict__ KlT)
{
    const int lin = blockIdx.x;
    const int which = lin >> 8;
    const int t = lin & 255;
    const int stile = (t & 7) | ((t >> 5) << 3);
    const int jtile = (t >> 3) & 3;
    const int tid = threadIdx.x, wv = tid >> 6, lane = tid & 63;
    const int li = lane & 15, g = lane >> 4;
    const int wr = wv >> 1, wc = wv & 1;

    __shared__ __align__(16) char LBp[65536];

    const unsigned short* __restrict__ pAh =
        CA + (size_t)which * 5242880 + (size_t)stile * 40960 + tid * 8;
    const unsigned short* __restrict__ pAl = pAh + 2621440;
    const unsigned short* __restrict__ pWh =
        CW + (size_t)which * 327680 + (size_t)jtile * 40960 + tid * 8;
    const unsigned short* __restrict__ pWl = pWh + 163840;

#define STAGEP(ch, bofs) {                                                    \
        char* db = LBp + (bofs) + wv * 1024;                                  \
        const size_t co = (size_t)(ch) * 4096;                                \
        gload16(pAh + co,        db);                                         \
        gload16(pAh + co + 2048, db + 4096);                                  \
        gload16(pAl + co,        db + 8192);                                  \
        gload16(pAl + co + 2048, db + 12288);                                 \
        gload16(pWh + co,        db + 16384);                                 \
        gload16(pWh + co + 2048, db + 20480);                                 \
        gload16(pWl + co,        db + 24576);                                 \
        gload16(pWl + co + 2048, db + 28672);                                 \
    }

    int offA[4], offW[4];
#pragma unroll
    for (int ssub = 0; ssub < 4; ++ssub) {
        const int r = wr * 64 + ssub * 16 + li;
        offA[ssub] = r * 64 + ((g ^ ((r >> 1) & 3)) << 4);
    }
#pragma unroll
    for (int jsub = 0; jsub < 4; ++jsub) {
        const int n = wc * 64 + jsub * 16 + li;
        offW[jsub] = n * 64 + ((g ^ ((n >> 1) & 3)) << 4);
    }

    f32x4 acc[4][4];
#pragma unroll
    for (int i = 0; i < 4; ++i)
#pragma unroll
        for (int j = 0; j < 4; ++j) acc[i][j] = (f32x4){0.f, 0.f, 0.f, 0.f};

    STAGEP(0, 0)
    __syncthreads();

#pragma unroll 1
    for (int ch = 0; ch < 10; ++ch) {
        const int bofs = (ch & 1) * 32768;
        if (ch < 9) STAGEP(ch + 1, bofs ^ 32768)
        const char* bp = LBp + bofs;
        s16x8 ah[4], al[4], wh[4], wl[4];
#pragma unroll
        for (int ssub = 0; ssub < 4; ++ssub) {
            ah[ssub] = *(const s16x8*)(bp + offA[ssub]);
            al[ssub] = *(const s16x8*)(bp + 8192 + offA[ssub]);
        }
#pragma unroll
        for (int jsub = 0; jsub < 4; ++jsub) {
            wh[jsub] = *(const s16x8*)(bp + 16384 + offW[jsub]);
            wl[jsub] = *(const s16x8*)(bp + 24576 + offW[jsub]);
        }
        __builtin_amdgcn_s_setprio(1);
#pragma unroll
        for (int ssub = 0; ssub < 4; ++ssub)
#pragma unroll
            for (int jsub = 0; jsub < 4; ++jsub) {
                acc[ssub][jsub] = MFMA16(ah[ssub], wh[jsub], acc[ssub][jsub], 0, 0, 0);
                acc[ssub][jsub] = MFMA16(ah[ssub], wl[jsub], acc[ssub][jsub], 0, 0, 0);
                acc[ssub][jsub] = MFMA16(al[ssub], wh[jsub], acc[ssub][jsub], 0, 0, 0);
            }
        __builtin_amdgcn_s_setprio(0);
        __syncthreads();
    }
#undef STAGEP

    const int jgbase = jtile * 128 + wc * 64 + li;
    const int sbase0 = stile * 128 + wr * 64 + 4 * g;
#pragma unroll
    for (int jsub = 0; jsub < 4; ++jsub) {
        const int jgg = jgbase + jsub * 16;
        const int d = jgg >> 3, hh = jgg & 7;
#pragma unroll
        for (int ssub = 0; ssub < 4; ++ssub) {
            const f32x4 v = acc[ssub][jsub];
            const int sg0 = sbase0 + ssub * 16;
            const int bbv = sg0 >> 11;
            const int bhn = bbv * 8 + hh;
            const int sl0 = sg0 & 2047;
            if (which == 0) {
                const size_t o = ((size_t)bhn * 2048 + sl0) * 64 + d;
#pragma unroll
                for (int r = 0; r < 4; ++r) {
                    const float val = v[r];
                    const unsigned short hi = f2bf(val);
                    Qh[o + r * 64] = hi;
                    Ql[o + r * 64] = f2bf(val - bf2f(hi));
                }
            } else {
                const int tile = sl0 >> 6, tt0 = sl0 & 63;
                const size_t tb = ((size_t)(bhn * 32 + tile)) << 12;
#pragma unroll
                for (int r = 0; r < 4; ++r) {
                    const int tt = tt0 + r;
                    const size_t o = tb + tt * 64 + (((d >> 3) ^ (tt & 7)) << 3) + (d & 7);
                    const float val = v[r];
                    const unsigned short hi = f2bf(val);
                    KhT[o] = hi;
                    KlT[o] = f2bf(val - bf2f(hi));
                }
            }
        }
    }
}

// ---------------------------------------------------------------------------
// Kernel 2b: MFMA V projection (1-term). V stored in 32x32-PV slot order:
// within row d: slot s_pre = 2*(t>>4) | ((t>>2)&1), j = 4*((t>>3)&1)+(t&3),
// stored slot = s_pre ^ (d&7).
// ---------------------------------------------------------------------------
__global__ __launch_bounds__(256) void proj_v_kernel(
    const unsigned short* __restrict__ CA, const unsigned short* __restrict__ CW,
    unsigned short* __restrict__ VtT)
{
    const int t = blockIdx.x;
    const int stile = (t & 7) | ((t >> 5) << 3);
    const int jtile = (t >> 3) & 3;
    const int tid = threadIdx.x, wv = tid >> 6, lane = tid & 63;
    const int li = lane & 15, g = lane >> 4;
    const int wr = wv >> 1, wc = wv & 1;

    __shared__ __align__(16) char LBv[32768];

    const unsigned short* __restrict__ pAh =
        CA + (size_t)1 * 5242880 + (size_t)stile * 40960 + tid * 8;
    const unsigned short* __restrict__ pWh =
        CW + (size_t)2 * 327680 + (size_t)jtile * 40960 + tid * 8;

#define STAGEV(ch, bofs) {                                                    \
        char* db = LBv + (bofs) + wv * 1024;                                  \
        const size_t co = (size_t)(ch) * 4096;                                \
        gload16(pAh + co,        db);                                         \
        gload16(pAh + co + 2048, db + 4096);                                  \
        gload16(pWh + co,        db + 8192);                                  \
        gload16(pWh + co + 2048, db + 12288);                                 \
    }

    int offA[4], offW[4];
#pragma unroll
    for (int ssub = 0; ssub < 4; ++ssub) {
        const int r = wr * 64 + ssub * 16 + li;
        offA[ssub] = r * 64 + ((g ^ ((r >> 1) & 3)) << 4);
    }
#pragma unroll
    for (int jsub = 0; jsub < 4; ++jsub) {
        const int n = wc * 64 + jsub * 16 + li;
        offW[jsub] = 8192 + n * 64 + ((g ^ ((n >> 1) & 3)) << 4);
    }

    f32x4 acc[4][4];
#pragma unroll
    for (int i = 0; i < 4; ++i)
#pragma unroll
        for (int j = 0; j < 4; ++j) acc[i][j] = (f32x4){0.f, 0.f, 0.f, 0.f};

    STAGEV(0, 0)
    __syncthreads();

#pragma unroll 1
    for (int ch = 0; ch < 10; ++ch) {
        const int bofs = (ch & 1) * 16384;
        if (ch < 9) STAGEV(ch + 1, bofs ^ 16384)
        const char* bp = LBv + bofs;
        s16x8 ah[4], wh[4];
#pragma unroll
        for (int ssub = 0; ssub < 4; ++ssub)
            ah[ssub] = *(const s16x8*)(bp + offA[ssub]);
#pragma unroll
        for (int jsub = 0; jsub < 4; ++jsub)
            wh[jsub] = *(const s16x8*)(bp + offW[jsub]);
        __builtin_amdgcn_s_setprio(1);
#pragma unroll
        for (int ssub = 0; ssub < 4; ++ssub)
#pragma unroll
            for (int jsub = 0; jsub < 4; ++jsub)
                acc[ssub][jsub] = MFMA16(ah[ssub], wh[jsub], acc[ssub][jsub], 0, 0, 0);
        __builtin_amdgcn_s_setprio(0);
        __syncthreads();
    }
#undef STAGEV

    const int jgbase = jtile * 128 + wc * 64 + li;
    const int sbase0 = stile * 128 + wr * 64 + 4 * g;
#pragma unroll
    for (int jsub = 0; jsub < 4; ++jsub) {
        const int jgg = jgbase + jsub * 16;
        const int d = jgg >> 3, hh = jgg & 7;
#pragma unroll
        for (int ssub = 0; ssub < 4; ++ssub) {
            const f32x4 v = acc[ssub][jsub];
            const int sg0 = sbase0 + ssub * 16;
            const int bbv = sg0 >> 11;
            const int bhn = bbv * 8 + hh;
            const int sl0 = sg0 & 2047;
            const int tile = sl0 >> 6, tin0 = sl0 & 63;   // tin0 % 4 == 0
            const size_t tb = ((size_t)(bhn * 32 + tile)) << 12;
            const int s_pre = ((tin0 >> 4) << 1) | ((tin0 >> 2) & 1);
            const int j0 = ((tin0 >> 3) & 1) * 4;
            const size_t o = tb + (size_t)d * 64 + ((s_pre ^ (d & 7)) << 3) + j0;
            u16x4 pk;
#pragma unroll
            for (int r = 0; r < 4; ++r) pk[r] = f2bf(v[r]);
            *(u16x4*)(VtT + o) = pk;
        }
    }
}

// ---------------------------------------------------------------------------
// Kernel 3: 32x32-MFMA flash attention. 4 waves x 32 q-rows, 512 blocks
// (2/CU, 2 waves/SIMD, VGPR budget 256). 3-ring + counted vmcnt(6),
// setprio, XCD swizzle, defer-max, raw exp2. LDS reads per q halved.
// ---------------------------------------------------------------------------
__global__ __launch_bounds__(256, 2) void attn32_kernel(
    const unsigned short* __restrict__ Qh, const unsigned short* __restrict__ Ql,
    const unsigned short* __restrict__ KhT, const unsigned short* __restrict__ KlT,
    const unsigned short* __restrict__ VtT, const unsigned int* __restrict__ BiasT,
    unsigned short* __restrict__ AOb)
{
    const int lin = blockIdx.x + 16 * blockIdx.y;
    const int qt = (lin >> 3) & 15;
    const int bh = (lin & 7) + ((lin >> 7) << 3);
    const int bb = bh >> 3, hh = bh & 7;
    const int tid = threadIdx.x;
    const int wv = tid >> 6, lane = tid & 63;
    const int hi = lane >> 5, l31 = lane & 31, l7 = lane & 7;
    const int q = qt * 128 + wv * 32 + l31;

    __shared__ __align__(16) char LB[3 * BUFB];       // 72 KB

    // ---- Q fragments: B-operand col=q, slot(hi,j) -> d = c*16 + hi*8 + j
    const size_t qoff = ((size_t)bh * SD_ + q) * DH + hi * 8;
    s16x8 qh[4], ql[4];
#pragma unroll
    for (int c = 0; c < 4; ++c) {
        qh[c] = *(const s16x8*)(Qh + qoff + c * 16);
        ql[c] = *(const s16x8*)(Ql + qoff + c * 16);
    }

    const unsigned short* __restrict__ sKh = KhT + ((size_t)bh << 17) + tid * 8;
    const unsigned short* __restrict__ sKl = KlT + ((size_t)bh << 17) + tid * 8;
    const unsigned short* __restrict__ sVt = VtT + ((size_t)bh << 17) + tid * 8;

    // per-lane LDS read offsets (bytes): row (lane&31), slot (2c+hi)^(lane&7)
    int koff[4];
#pragma unroll
    for (int c = 0; c < 4; ++c)
        koff[c] = l31 * 128 + (((2 * c + hi) ^ l7) << 4);

    // bias base (uint4 units)
    const int qg = q >> 5;
    const size_t blane4 = (size_t)hi * 32 + l31;
    const uint4* __restrict__ Bias4 = (const uint4*)BiasT;

#define BIASLOAD(T, R0, R1, R2, R3) {                                         \
        const size_t b4 = (((size_t)qg * 32 + (T)) * 4) * 64 + blane4;        \
        R0 = Bias4[b4];        R1 = Bias4[b4 + 64];                           \
        R2 = Bias4[b4 + 128];  R3 = Bias4[b4 + 192];                          \
    }
#define STAGE(tile, boff)                                                     \
    {                                                                         \
        char* db = LB + (boff) + wv * 1024;                                   \
        const size_t toff = (size_t)(tile) << 12;                             \
        gload16(sKh + toff,        db);                                       \
        gload16(sKh + toff + 2048, db + 4096);                                \
        gload16(sKl + toff,        db + 8192);                                \
        gload16(sKl + toff + 2048, db + 12288);                               \
        gload16(sVt + toff,        db + 16384);                               \
        gload16(sVt + toff + 2048, db + 20480);                               \
    }

    float m = -INFINITY, lacc = 0.f;
    f32x16 O0, O1;
#pragma unroll
    for (int i = 0; i < 16; ++i) { O0[i] = 0.f; O1[i] = 0.f; }

    uint4 cB0, cB1, cB2, cB3, nB0, nB1, nB2, nB3;

#define UNPKW(W, S, r)                                                        \
        S[r]     = __uint_as_float((W) << 16);                                \
        S[r + 1] = __uint_as_float((W) & 0xFFFF0000u);

#define ITER(IT, C0_, C1_, C2_, C3_, N0_, N1_, N2_, N3_)                      \
    {                                                                         \
        BIASLOAD(((IT) + 1) & 31, N0_, N1_, N2_, N3_)                         \
        STAGE(((IT) + 2) & 31, cs)                                            \
        f32x16 sA, sB;                                                        \
        UNPKW(C0_.x, sA, 0)  UNPKW(C0_.y, sA, 2)                              \
        UNPKW(C0_.z, sA, 4)  UNPKW(C0_.w, sA, 6)                              \
        UNPKW(C1_.x, sA, 8)  UNPKW(C1_.y, sA, 10)                             \
        UNPKW(C1_.z, sA, 12) UNPKW(C1_.w, sA, 14)                             \
        UNPKW(C2_.x, sB, 0)  UNPKW(C2_.y, sB, 2)                              \
        UNPKW(C2_.z, sB, 4)  UNPKW(C2_.w, sB, 6)                              \
        UNPKW(C3_.x, sB, 8)  UNPKW(C3_.y, sB, 10)                             \
        UNPKW(C3_.z, sB, 12) UNPKW(C3_.w, sB, 14)                             \
        __builtin_amdgcn_s_setprio(1);                                        \
        _Pragma("unroll")                                                     \
        for (int c = 0; c < 4; ++c) {                                         \
            const s16x8 kh0 = *(const s16x8*)(LB + cc + koff[c]);             \
            const s16x8 kh1 = *(const s16x8*)(LB + cc + 4096 + koff[c]);      \
            const s16x8 kl0 = *(const s16x8*)(LB + cc + 8192 + koff[c]);      \
            const s16x8 kl1 = *(const s16x8*)(LB + cc + 12288 + koff[c]);     \
            sA = MFMA32(kh0, qh[c], sA, 0, 0, 0);                             \
            sA = MFMA32(kh0, ql[c], sA, 0, 0, 0);                             \
            sA = MFMA32(kl0, qh[c], sA, 0, 0, 0);                             \
            sB = MFMA32(kh1, qh[c], sB, 0, 0, 0);                             \
            sB = MFMA32(kh1, ql[c], sB, 0, 0, 0);                             \
            sB = MFMA32(kl1, qh[c], sB, 0, 0, 0);                             \
        }                                                                     \
        __builtin_amdgcn_s_setprio(0);                                        \
        float tv[32];                                                         \
        _Pragma("unroll")                                                     \
        for (int i = 0; i < 16; ++i) { tv[i] = sA[i]; tv[16 + i] = sB[i]; }   \
        _Pragma("unroll")                                                     \
        for (int st = 16; st > 0; st >>= 1)                                   \
            _Pragma("unroll")                                                 \
            for (int i = 0; i < st; ++i) tv[i] = fmaxf(tv[i], tv[i + st]);    \
        const float tmax = tv[0];                                             \
        if (!__all(tmax <= m + DEFER_THR)) {                                  \
            float r = fmaxf(tmax, __shfl_xor(tmax, 32));                      \
            const float mn  = fmaxf(m, r);                                    \
            const float scl = fexp2(m - mn);                                  \
            m = mn;                                                           \
            _Pragma("unroll")                                                 \
            for (int i = 0; i < 16; ++i) { O0[i] *= scl; O1[i] *= scl; }      \
            lacc *= scl;                                                      \
        }                                                                     \
        _Pragma("unroll")                                                     \
        for (int i = 0; i < 16; ++i) {                                        \
            sA[i] = fexp2(sA[i] - m);                                         \
            sB[i] = fexp2(sB[i] - m);                                         \
        }                                                                     \
        float sv[32];                                                         \
        _Pragma("unroll")                                                     \
        for (int i = 0; i < 16; ++i) { sv[i] = sA[i]; sv[16 + i] = sB[i]; }   \
        _Pragma("unroll")                                                     \
        for (int st = 16; st > 0; st >>= 1)                                   \
            _Pragma("unroll")                                                 \
            for (int i = 0; i < st; ++i) sv[i] += sv[i + st];                 \
        lacc += sv[0];                                                        \
        union { s16x8 v; unsigned int w[4]; } P0, P1, P2, P3;                 \
        asm("v_cvt_pk_bf16_f32 %0, %1, %2" : "=v"(P0.w[0]) : "v"(sA[0]),  "v"(sA[1]));  \
        asm("v_cvt_pk_bf16_f32 %0, %1, %2" : "=v"(P0.w[1]) : "v"(sA[2]),  "v"(sA[3]));  \
        asm("v_cvt_pk_bf16_f32 %0, %1, %2" : "=v"(P0.w[2]) : "v"(sA[4]),  "v"(sA[5]));  \
        asm("v_cvt_pk_bf16_f32 %0, %1, %2" : "=v"(P0.w[3]) : "v"(sA[6]),  "v"(sA[7]));  \
        asm("v_cvt_pk_bf16_f32 %0, %1, %2" : "=v"(P1.w[0]) : "v"(sA[8]),  "v"(sA[9]));  \
        asm("v_cvt_pk_bf16_f32 %0, %1, %2" : "=v"(P1.w[1]) : "v"(sA[10]), "v"(sA[11])); \
        asm("v_cvt_pk_bf16_f32 %0, %1, %2" : "=v"(P1.w[2]) : "v"(sA[12]), "v"(sA[13])); \
        asm("v_cvt_pk_bf16_f32 %0, %1, %2" : "=v"(P1.w[3]) : "v"(sA[14]), "v"(sA[15])); \
        asm("v_cvt_pk_bf16_f32 %0, %1, %2" : "=v"(P2.w[0]) : "v"(sB[0]),  "v"(sB[1]));  \
        asm("v_cvt_pk_bf16_f32 %0, %1, %2" : "=v"(P2.w[1]) : "v"(sB[2]),  "v"(sB[3]));  \
        asm("v_cvt_pk_bf16_f32 %0, %1, %2" : "=v"(P2.w[2]) : "v"(sB[4]),  "v"(sB[5]));  \
        asm("v_cvt_pk_bf16_f32 %0, %1, %2" : "=v"(P2.w[3]) : "v"(sB[6]),  "v"(sB[7]));  \
        asm("v_cvt_pk_bf16_f32 %0, %1, %2" : "=v"(P3.w[0]) : "v"(sB[8]),  "v"(sB[9]));  \
        asm("v_cvt_pk_bf16_f32 %0, %1, %2" : "=v"(P3.w[1]) : "v"(sB[10]), "v"(sB[11])); \
        asm("v_cvt_pk_bf16_f32 %0, %1, %2" : "=v"(P3.w[2]) : "v"(sB[12]), "v"(sB[13])); \
        asm("v_cvt_pk_bf16_f32 %0, %1, %2" : "=v"(P3.w[3]) : "v"(sB[14]), "v"(sB[15])); \
        __builtin_amdgcn_s_setprio(1);                                        \
        {                                                                     \
            const s16x8 v0 = *(const s16x8*)(LB + cc + 16384 + koff[0]);      \
            const s16x8 v1 = *(const s16x8*)(LB + cc + 16384 + koff[1]);      \
            const s16x8 v2 = *(const s16x8*)(LB + cc + 16384 + koff[2]);      \
            const s16x8 v3 = *(const s16x8*)(LB + cc + 16384 + koff[3]);      \
            O0 = MFMA32(v0, P0.v, O0, 0, 0, 0);                               \
            O0 = MFMA32(v1, P1.v, O0, 0, 0, 0);                               \
            O0 = MFMA32(v2, P2.v, O0, 0, 0, 0);                               \
            O0 = MFMA32(v3, P3.v, O0, 0, 0, 0);                               \
            const s16x8 w0 = *(const s16x8*)(LB + cc + 20480 + koff[0]);      \
            const s16x8 w1 = *(const s16x8*)(LB + cc + 20480 + koff[1]);      \
            const s16x8 w2 = *(const s16x8*)(LB + cc + 20480 + koff[2]);      \
            const s16x8 w3 = *(const s16x8*)(LB + cc + 20480 + koff[3]);      \
            O1 = MFMA32(w0, P0.v, O1, 0, 0, 0);                               \
            O1 = MFMA32(w1, P1.v, O1, 0, 0, 0);                               \
            O1 = MFMA32(w2, P2.v, O1, 0, 0, 0);                               \
            O1 = MFMA32(w3, P3.v, O1, 0, 0, 0);                               \
        }                                                                     \
        __builtin_amdgcn_s_setprio(0);                                        \
        asm volatile("s_waitcnt vmcnt(6)" ::: "memory");                      \
        __builtin_amdgcn_s_barrier();                                         \
        __builtin_amdgcn_sched_barrier(0);                                    \
        cc += BUFB; if (cc == 3 * BUFB) cc = 0;                               \
        cs += BUFB; if (cs == 3 * BUFB) cs = 0;                               \
    }

    int cc = 0, cs = 2 * BUFB;

    // prologue: bias0 + tiles 0,1
    BIASLOAD(0, cB0, cB1, cB2, cB3)
    STAGE(0, 0)
    STAGE(1, BUFB)
    asm volatile("s_waitcnt vmcnt(6)" ::: "memory");   // bias0 + tile0 landed
    __builtin_amdgcn_s_barrier();
    __builtin_amdgcn_sched_barrier(0);

#pragma unroll 1
    for (int it = 0; it < 32; it += 2) {
        ITER(it,     cB0, cB1, cB2, cB3, nB0, nB1, nB2, nB3)
        ITER(it + 1, nB0, nB1, nB2, nB3, cB0, cB1, cB2, cB3)
    }

    // ---- finish l (lane<->lane+32), normalize + store bf16 tiled AO ----
    lacc += __shfl_xor(lacc, 32);
    const float rl = 1.f / lacc;
    const int row = bb * 2048 + q;
    const int r128 = row & 127;                        // = wv*32 + l31
    const int xr = (r128 >> 1) & 3;
    unsigned short* __restrict__ ab = AOb + ((size_t)(row >> 7)) * 65536
                                    + r128 * 32 + 4 * hi;
#pragma unroll
    for (int dt = 0; dt < 2; ++dt) {
        const int ch = hh * 2 + dt;
#pragma unroll
        for (int rg = 0; rg < 4; ++rg) {
            u16x4 pk;
#pragma unroll
            for (int c = 0; c < 4; ++c)
                pk[c] = f2bf((dt ? O1[4 * rg + c] : O0[4 * rg + c]) * rl);
            *(u16x4*)(ab + (size_t)ch * 4096 + ((rg ^ xr) << 3)) = pk;
        }
    }
#undef STAGE
#undef BIASLOAD
#undef UNPKW
#undef ITER
}

// ---------------------------------------------------------------------------
// Kernel 4: MFMA epilogue GEMM (unchanged).
// ---------------------------------------------------------------------------
__global__ __launch_bounds__(256) void epi_mfma_kernel(
    const unsigned short* __restrict__ AOb, const unsigned short* __restrict__ WOT,
    float* __restrict__ out)
{
    const int stile = blockIdx.x, jtile = blockIdx.y;
    const int tid = threadIdx.x, wv = tid >> 6, lane = tid & 63;
    const int li = lane & 15, g = lane >> 4;

    __shared__ __align__(16) char LBe[24576];

    const unsigned short* __restrict__ pA =
        AOb + (size_t)(stile >> 1) * 65536 + (stile & 1) * 2048 + tid * 8;
    const unsigned short* __restrict__ pW = WOT + (size_t)jtile * 65536 + tid * 8;

#define STAGEE(ch, bofs) {                                                    \
        char* dbA = LBe + (bofs) + wv * 1024;                                 \
        const size_t co = (size_t)(ch) * 4096;                                \
        gload16(pA + co,        dbA);                                         \
        gload16(pW + co,        dbA + 4096);                                  \
        gload16(pW + co + 2048, dbA + 8192);                                  \
    }

    int offA[4], offW[2];
#pragma unroll
    for (int ssub = 0; ssub < 4; ++ssub) {
        const int r = ssub * 16 + li;
        offA[ssub] = r * 64 + ((g ^ ((r >> 1) & 3)) << 4);
    }
#pragma unroll
    for (int jsub = 0; jsub < 2; ++jsub) {
        const int n = wv * 32 + jsub * 16 + li;
        offW[jsub] = 4096 + n * 64 + ((g ^ ((n >> 1) & 3)) << 4);
    }

    f32x4 acc[4][2];
#pragma unroll
    for (int i = 0; i < 4; ++i)
#pragma unroll
        for (int j = 0; j < 2; ++j) acc[i][j] = (f32x4){0.f, 0.f, 0.f, 0.f};

    STAGEE(0, 0)
    __syncthreads();

#pragma unroll 1
    for (int ch = 0; ch < 16; ++ch) {
        const int bofs = (ch & 1) * 12288;
        if (ch < 15) STAGEE(ch + 1, bofs ^ 12288)
        const char* bp = LBe + bofs;
        s16x8 ah[4], wh[2];
#pragma unroll
        for (int ssub = 0; ssub < 4; ++ssub)
            ah[ssub] = *(const s16x8*)(bp + offA[ssub]);
#pragma unroll
        for (int jsub = 0; jsub < 2; ++jsub)
            wh[jsub] = *(const s16x8*)(bp + offW[jsub]);
        __builtin_amdgcn_s_setprio(1);
#pragma unroll
        for (int ssub = 0; ssub < 4; ++ssub)
#pragma unroll
            for (int jsub = 0; jsub < 2; ++jsub)
                acc[ssub][jsub] = MFMA16(ah[ssub], wh[jsub], acc[ssub][jsub], 0, 0, 0);
        __builtin_amdgcn_s_setprio(0);
        __syncthreads();
    }
#undef STAGEE

    const int nbase = jtile * 128 + wv * 32 + li;
    const int rbase = stile * 64 + 4 * g;
#pragma unroll
    for (int jsub = 0; jsub < 2; ++jsub) {
        const int o = nbase + jsub * 16;
        if (o < HIDIN) {
#pragma unroll
            for (int ssub = 0; ssub < 4; ++ssub) {
                const f32x4 v = acc[ssub][jsub];
                const int r0 = rbase + ssub * 16;
#pragma unroll
                for (int r = 0; r < 4; ++r)
                    out[(size_t)(r0 + r) * HIDIN + o] = v[r];
            }
        }
    }
}

// ---------------------------------------------------------------------------
extern "C" void kernel_launch(void* const* d_in, const int* in_sizes, int n_in,
                              void* d_out, int out_size, void* d_ws, size_t ws_size,
                              hipStream_t stream)
{
    const float* en  = (const float*)d_in[0];
    const float* de  = (const float*)d_in[1];
    const int*   mask = (const int*)d_in[2];
    const float* WQ  = (const float*)d_in[3];
    const float* WK  = (const float*)d_in[4];
    const float* WV  = (const float*)d_in[5];
    const float* WO  = (const float*)d_in[6];
    float* out = (float*)d_out;

    unsigned short* ws2 = (unsigned short*)d_ws;
    unsigned short* Qh  = ws2 + OF_QH;
    unsigned short* Ql  = ws2 + OF_QL;
    unsigned short* KhT = ws2 + OF_KH;
    unsigned short* KlT = ws2 + OF_KL;
    unsigned short* VtT = ws2 + OF_VT;
    unsigned short* CA  = ws2 + OF_CA;
    unsigned short* CW  = ws2 + OF_CW;
    unsigned short* WOT = ws2 + OF_WOT;
    unsigned short* AOb = CA;                                 // aliases conv-A (dead after proj)
    unsigned int*  BiasT = (unsigned int*)(CA + 4194304);     // aliases conv-A tail

    convA_kernel<<<dim3(320, 2), 256, 0, stream>>>(de, en, CA);
    convW_kernel<<<dim3(672), 256, 0, stream>>>(WQ, WK, WV, WO, CW, WOT);
    proj_qk_kernel<<<dim3(512), 256, 0, stream>>>(CA, CW, Qh, Ql, KhT, KlT);
    proj_v_kernel<<<dim3(256), 256, 0, stream>>>(CA, CW, VtT);
    bias_kernel<<<dim3(256), 256, 0, stream>>>(mask, BiasT);
    attn32_kernel<<<dim3(16, 32), 256, 0, stream>>>(Qh, Ql, KhT, KlT, VtT,
                                                    BiasT, AOb);
    epi_mfma_kernel<<<dim3(128, 3), 256, 0, stream>>>(AOb, WOT, out);
}